// Round 2
// baseline (423.854 us; speedup 1.0000x reference)
//
#include <hip/hip_runtime.h>

// CognitiveWorkspace: gate = sigmoid([H*Wq^T, mean_tag] * Wg^T + bg)
// S_out = S with: spoke += w_spoke, hub_priv += w_hub_priv,
//                 hub_shared = S*gate + w_hub_shared, tag += tag_in
// Output = [S_out (16384*6656 f32), gate (16384*512 f32)]

#define DM 2048      // d_model
#define DSZ 6656     // D_S
#define TAGOFF 5120
#define NTOK 16384   // B*T

__device__ __forceinline__ float sigmoidf_(float x) {
  return 1.0f / (1.0f + __expf(-x));
}

// ---------------------------------------------------------------------------
// Kernel G: 32 tokens per block, 256 threads.
//   phase 1: mean_tag -> ginT rows 64..127   (ginT layout [k][tok], stride 36)
//   phase 2: query    -> ginT rows 0..63     (LDS-staged Wq chunks, 2tok x 4q regs)
//   phase 3: gate     -> d_out gate region   (LDS-staged Wg chunks, 8tok x 8h regs)
// ---------------------------------------------------------------------------
__global__ __launch_bounds__(256) void cw_gate_kernel(
    const float* __restrict__ S, const float* __restrict__ H,
    const float* __restrict__ Wq, const float* __restrict__ Wg,
    const float* __restrict__ bg, const int* __restrict__ lip,
    float* __restrict__ gate_out)
{
  __shared__ float ginT[128 * 36];   // 18432 B  [k=0..127][tok=0..31]
  __shared__ float ldsbuf[8192];     // 32768 B  union: {Wq chunk + H^T chunk} / {Wg chunk}
  float* lds_w = ldsbuf;             // [64 j][64 q]
  float* lds_h = ldsbuf + 4096;      // [64 j][34] transposed H chunk (stride 34 keeps f2 aligned)

  const int tid = threadIdx.x;
  const int li = *lip;
  const int start = (li > 8) ? (li - 8) : 0;
  const int ntags = li - start;
  const float tscale = (ntags > 0) ? (1.0f / (float)ntags) : 0.0f;
  const int trs = TAGOFF + start * 64;
  const int tok0 = blockIdx.x * 32;

  // ---- phase 1: mean over past tags -> ginT[64+d][tok]
#pragma unroll
  for (int r = 0; r < 8; ++r) {
    int o = r * 256 + tid;        // 0..2047 = 32 tok x 64 d
    int tk = o >> 6;
    int d = o & 63;
    const float* sp = S + (size_t)(tok0 + tk) * DSZ + trs + d;
    float acc = 0.f;
    for (int g = 0; g < ntags; ++g) acc += sp[g * 64];
    ginT[(64 + d) * 36 + tk] = acc * tscale;
  }

  // ---- phase 2: query[q] = sum_j H[tok][j] * Wq[q][j]
  const int ql = tid & 15;  const int q0 = ql * 4;   // 4 q's per thread
  const int th = tid >> 4;  const int t0 = th * 2;   // 2 tokens per thread
  float a00 = 0.f, a01 = 0.f, a02 = 0.f, a03 = 0.f;
  float a10 = 0.f, a11 = 0.f, a12 = 0.f, a13 = 0.f;

  for (int jc = 0; jc < 32; ++jc) {
    __syncthreads();
    const int jg = jc * 64;
    // stage Wq chunk -> lds_w[j][q]  (dest-linear float4 writes, conflict-free)
#pragma unroll
    for (int r = 0; r < 4; ++r) {
      int t4 = r * 256 + tid;     // dest quad 0..1023; floats 4*t4: j=t4>>4, q=(t4&15)*4
      int j = t4 >> 4;
      int qq = (t4 & 15) * 4;
      float4 v;
      v.x = Wq[(size_t)(qq + 0) * DM + jg + j];
      v.y = Wq[(size_t)(qq + 1) * DM + jg + j];
      v.z = Wq[(size_t)(qq + 2) * DM + jg + j];
      v.w = Wq[(size_t)(qq + 3) * DM + jg + j];
      *reinterpret_cast<float4*>(&lds_w[t4 << 2]) = v;
    }
    // stage H chunk transposed -> lds_h[j][tok]
    {
      int tk = tid & 31;
      int j0 = (tid >> 5) * 8;
      const float* hp = H + (size_t)(tok0 + tk) * DM + jg + j0;
      float4 h0 = *reinterpret_cast<const float4*>(hp);
      float4 h1 = *reinterpret_cast<const float4*>(hp + 4);
      lds_h[(j0 + 0) * 34 + tk] = h0.x;
      lds_h[(j0 + 1) * 34 + tk] = h0.y;
      lds_h[(j0 + 2) * 34 + tk] = h0.z;
      lds_h[(j0 + 3) * 34 + tk] = h0.w;
      lds_h[(j0 + 4) * 34 + tk] = h1.x;
      lds_h[(j0 + 5) * 34 + tk] = h1.y;
      lds_h[(j0 + 6) * 34 + tk] = h1.z;
      lds_h[(j0 + 7) * 34 + tk] = h1.w;
    }
    __syncthreads();
#pragma unroll 8
    for (int j = 0; j < 64; ++j) {
      float4 w = *reinterpret_cast<const float4*>(&lds_w[(j << 6) + q0]);
      float2 h = *reinterpret_cast<const float2*>(&lds_h[j * 34 + t0]);
      a00 += h.x * w.x; a01 += h.x * w.y; a02 += h.x * w.z; a03 += h.x * w.w;
      a10 += h.y * w.x; a11 += h.y * w.y; a12 += h.y * w.z; a13 += h.y * w.w;
    }
  }
  // query -> ginT[q][tok]
  ginT[(q0 + 0) * 36 + t0] = a00;
  ginT[(q0 + 1) * 36 + t0] = a01;
  ginT[(q0 + 2) * 36 + t0] = a02;
  ginT[(q0 + 3) * 36 + t0] = a03;
  ginT[(q0 + 0) * 36 + t0 + 1] = a10;
  ginT[(q0 + 1) * 36 + t0 + 1] = a11;
  ginT[(q0 + 2) * 36 + t0 + 1] = a12;
  ginT[(q0 + 3) * 36 + t0 + 1] = a13;

  // ---- phase 3: gate[h] = sigmoid(sum_k gin[k] * Wg[h][k] + bg[h])
  const int hq = tid & 63;
  const int h0 = hq * 4;          // h quad a: 0..255
  const int h1 = 256 + hq * 4;    // h quad b: 256..511
  const int tq = tid >> 6;        // wave id
  const int tt0 = tq * 8;         // 8 tokens per wave
  float acc[8][8];
#pragma unroll
  for (int m = 0; m < 8; ++m)
#pragma unroll
    for (int n = 0; n < 8; ++n) acc[m][n] = 0.f;

  for (int kc = 0; kc < 8; ++kc) {
    __syncthreads();   // also guards ldsbuf reuse after phase 2
    // stage Wg chunk -> ldsbuf[k][h], k = kc*16..+15, 16x512 floats
#pragma unroll
    for (int r = 0; r < 8; ++r) {
      int t4 = r * 256 + tid;     // dest quad 0..2047: k=t4>>7, h=(t4&127)*4
      int k = t4 >> 7;
      int hh = (t4 & 127) * 4;
      int kg = kc * 16 + k;
      float4 v;
      v.x = Wg[(size_t)(hh + 0) * 128 + kg];
      v.y = Wg[(size_t)(hh + 1) * 128 + kg];
      v.z = Wg[(size_t)(hh + 2) * 128 + kg];
      v.w = Wg[(size_t)(hh + 3) * 128 + kg];
      *reinterpret_cast<float4*>(&ldsbuf[t4 << 2]) = v;
    }
    __syncthreads();
#pragma unroll 4
    for (int k = 0; k < 16; ++k) {
      int kg = kc * 16 + k;
      float4 wa = *reinterpret_cast<const float4*>(&ldsbuf[(k << 9) + h0]);
      float4 wb = *reinterpret_cast<const float4*>(&ldsbuf[(k << 9) + h1]);
      float4 ga = *reinterpret_cast<const float4*>(&ginT[kg * 36 + tt0]);
      float4 gb = *reinterpret_cast<const float4*>(&ginT[kg * 36 + tt0 + 4]);
      float gm[8] = {ga.x, ga.y, ga.z, ga.w, gb.x, gb.y, gb.z, gb.w};
#pragma unroll
      for (int m = 0; m < 8; ++m) {
        acc[m][0] += gm[m] * wa.x;
        acc[m][1] += gm[m] * wa.y;
        acc[m][2] += gm[m] * wa.z;
        acc[m][3] += gm[m] * wa.w;
        acc[m][4] += gm[m] * wb.x;
        acc[m][5] += gm[m] * wb.y;
        acc[m][6] += gm[m] * wb.z;
        acc[m][7] += gm[m] * wb.w;
      }
    }
  }
  float4 bga = *reinterpret_cast<const float4*>(&bg[h0]);
  float4 bgb = *reinterpret_cast<const float4*>(&bg[h1]);
#pragma unroll
  for (int m = 0; m < 8; ++m) {
    size_t grow = (size_t)(tok0 + tt0 + m) * 512;
    float4 oa, ob;
    oa.x = sigmoidf_(acc[m][0] + bga.x);
    oa.y = sigmoidf_(acc[m][1] + bga.y);
    oa.z = sigmoidf_(acc[m][2] + bga.z);
    oa.w = sigmoidf_(acc[m][3] + bga.w);
    ob.x = sigmoidf_(acc[m][4] + bgb.x);
    ob.y = sigmoidf_(acc[m][5] + bgb.y);
    ob.z = sigmoidf_(acc[m][6] + bgb.z);
    ob.w = sigmoidf_(acc[m][7] + bgb.w);
    *reinterpret_cast<float4*>(&gate_out[grow + h0]) = oa;
    *reinterpret_cast<float4*>(&gate_out[grow + h1]) = ob;
  }
}

// ---------------------------------------------------------------------------
// Kernel C: streaming rewrite of S (float4 grid-stride), region-conditional.
//   Region boundaries are multiples of 64 floats -> every float4 is in one region.
// ---------------------------------------------------------------------------
__global__ __launch_bounds__(256) void cw_write_kernel(
    const float* __restrict__ S,
    const float* __restrict__ w_spoke, const float* __restrict__ w_hub_priv,
    const float* __restrict__ w_hub_shared, const float* __restrict__ tg,
    const int* __restrict__ lip, const float* __restrict__ gate,
    float* __restrict__ outS)
{
  const int li = *lip;
  const unsigned sp0 = (unsigned)(li * 32), sp1 = sp0 + 32u;          // spoke (quads)
  const unsigned hp0 = 768u + (unsigned)(li * 16), hp1 = hp0 + 16u;   // hub_priv
  const unsigned hs0 = 1152u, hs1 = 1280u;                            // hub_shared
  const unsigned tg0 = 1280u + (unsigned)(li * 16), tg1 = tg0 + 16u;  // tag
  const unsigned rowq = DSZ / 4;                 // 1664
  const unsigned total = (unsigned)NTOK * rowq;  // 27262976

  const float4* S4 = reinterpret_cast<const float4*>(S);
  const float4* SP4 = reinterpret_cast<const float4*>(w_spoke);
  const float4* HP4 = reinterpret_cast<const float4*>(w_hub_priv);
  const float4* HS4 = reinterpret_cast<const float4*>(w_hub_shared);
  const float4* TG4 = reinterpret_cast<const float4*>(tg);
  const float4* G4 = reinterpret_cast<const float4*>(gate);
  float4* O4 = reinterpret_cast<float4*>(outS);

  for (unsigned i = blockIdx.x * 256u + threadIdx.x; i < total;
       i += gridDim.x * 256u) {
    unsigned tok = i / rowq;            // const-div -> magic multiply
    unsigned c = i - tok * rowq;
    float4 s = S4[i];
    float4 o = s;
    if (c >= hs0 && c < hs1) {
      unsigned off = tok * 128u + (c - hs0);
      float4 g = G4[off];
      float4 w = HS4[off];
      o.x = s.x * g.x + w.x;
      o.y = s.y * g.y + w.y;
      o.z = s.z * g.z + w.z;
      o.w = s.w * g.w + w.w;
    } else if (c >= sp0 && c < sp1) {
      float4 w = SP4[tok * 32u + (c - sp0)];
      o.x += w.x; o.y += w.y; o.z += w.z; o.w += w.w;
    } else if (c >= hp0 && c < hp1) {
      float4 w = HP4[tok * 16u + (c - hp0)];
      o.x += w.x; o.y += w.y; o.z += w.z; o.w += w.w;
    } else if (c >= tg0 && c < tg1) {
      float4 w = TG4[tok * 16u + (c - tg0)];
      o.x += w.x; o.y += w.y; o.z += w.z; o.w += w.w;
    }
    O4[i] = o;
  }
}

extern "C" void kernel_launch(void* const* d_in, const int* in_sizes, int n_in,
                              void* d_out, int out_size, void* d_ws, size_t ws_size,
                              hipStream_t stream) {
  (void)in_sizes; (void)n_in; (void)out_size; (void)d_ws; (void)ws_size;
  const float* S            = (const float*)d_in[0];
  const float* H            = (const float*)d_in[1];
  const float* w_spoke      = (const float*)d_in[2];
  const float* w_hub_priv   = (const float*)d_in[3];
  const float* w_hub_shared = (const float*)d_in[4];
  const float* tg           = (const float*)d_in[5];
  const float* Wq           = (const float*)d_in[6];
  const float* Wg           = (const float*)d_in[7];
  const float* bg           = (const float*)d_in[8];
  const int*   lip          = (const int*)d_in[9];

  float* outS = (float*)d_out;
  float* gate_out = outS + (size_t)NTOK * DSZ;   // gate output slot

  cw_gate_kernel<<<NTOK / 32, 256, 0, stream>>>(S, H, Wq, Wg, bg, lip, gate_out);
  cw_write_kernel<<<4096, 256, 0, stream>>>(S, w_spoke, w_hub_priv, w_hub_shared,
                                            tg, lip, gate_out, outS);
}

// Round 4
// 327.329 us; speedup vs baseline: 1.2949x; 1.2949x over previous
//
#include <hip/hip_runtime.h>
#include <hip/hip_bf16.h>

// CognitiveWorkspace fused kernels.
// K1: gate = sigmoid([H*Wq^T, mean_tag]*Wg^T + bg) via bf16 MFMA -> d_out gate.
// K2: streams all of S -> out with region-conditional adds; hub region reads
//     gate back from d_out (round-2-proven ownership structure).

#define DM 2048      // d_model
#define DSZ 6656     // D_S
#define TAGOFF 5120
#define NTOK 16384   // B*T
#define DHS 512      // d_hub_shared

typedef __attribute__((ext_vector_type(8))) short bf16x8;
typedef __attribute__((ext_vector_type(4))) float f32x4;

__device__ __forceinline__ float sigmoidf_(float x) {
  return 1.0f / (1.0f + __expf(-x));
}
__device__ __forceinline__ short f2bf(float x) {
  return (short)__bfloat16_as_ushort(__float2bfloat16(x));
}
// load 8 consecutive fp32, convert to bf16x8 fragment (compiler fuses to cvt_pk)
__device__ __forceinline__ bf16x8 load_bf8(const float* p) {
  float4 a = *reinterpret_cast<const float4*>(p);
  float4 b = *reinterpret_cast<const float4*>(p + 4);
  bf16x8 r;
  r[0] = f2bf(a.x); r[1] = f2bf(a.y); r[2] = f2bf(a.z); r[3] = f2bf(a.w);
  r[4] = f2bf(b.x); r[5] = f2bf(b.y); r[6] = f2bf(b.z); r[7] = f2bf(b.w);
  return r;
}

// ---------------------------------------------------------------------------
// K1: 32 tokens/block, 256 threads (4 waves).
//   phase 1: mean_tag -> gin[tok][64..127]
//   phase 2: query = H*Wq^T via MFMA (K=2048) -> gin[tok][0..63]
//   phase 3: gate = sigmoid(gin*Wg^T + bg) via MFMA (K=128) -> gate_out
// MFMA 16x16x32 bf16 layouts (m89-verified): A/B: row(col) = lane&15,
// k = (lane>>4)*8 + e;  C/D: col = lane&15, row = (lane>>4)*4 + reg.
// ---------------------------------------------------------------------------
__global__ __launch_bounds__(256) void cw_gate_kernel(
    const float* __restrict__ S, const float* __restrict__ H,
    const float* __restrict__ Wq, const float* __restrict__ Wg,
    const float* __restrict__ bg, const int* __restrict__ lip,
    float* __restrict__ gate_out)
{
  __shared__ float gin[32][132];   // stride 132 -> 2-way bank alias (free)

  const int tid = threadIdx.x;
  const int li = *lip;
  const int start = (li > 8) ? (li - 8) : 0;
  const int ntags = li - start;
  const float tscale = (ntags > 0) ? (1.0f / (float)ntags) : 0.0f;
  const int trs = TAGOFF + start * 64;
  const int tok0 = blockIdx.x * 32;

  // ---- phase 1: mean over past tags
#pragma unroll
  for (int r = 0; r < 8; ++r) {
    int o = r * 256 + tid;          // 32 tok x 64 d
    int tk = o >> 6, d = o & 63;
    const float* sp = S + (size_t)(tok0 + tk) * DSZ + trs + d;
    float acc = 0.f;
    for (int g = 0; g < ntags; ++g) acc += sp[g * 64];
    gin[tk][64 + d] = acc * tscale;
  }

  const int w = tid >> 6;
  const int l = tid & 63;
  const int l15 = l & 15, l4 = l >> 4;

  // ---- phase 2: query = H * Wq^T  (wave tiles: mt = w&1, q-tiles (w>>1)*2,+1)
  {
    const int mt = w & 1;
    const int q0 = (w >> 1) * 32;
    const float* ha  = H + (size_t)(tok0 + mt * 16 + l15) * DM + l4 * 8;
    const float* wq0 = Wq + (size_t)(q0 + l15) * DM + l4 * 8;
    const float* wq1 = wq0 + (size_t)16 * DM;
    f32x4 acc0 = {0.f, 0.f, 0.f, 0.f};
    f32x4 acc1 = {0.f, 0.f, 0.f, 0.f};
#pragma unroll 2
    for (int ks = 0; ks < 64; ++ks) {
      bf16x8 af = load_bf8(ha + ks * 32);
      bf16x8 b0 = load_bf8(wq0 + ks * 32);
      bf16x8 b1 = load_bf8(wq1 + ks * 32);
      acc0 = __builtin_amdgcn_mfma_f32_16x16x32_bf16(af, b0, acc0, 0, 0, 0);
      acc1 = __builtin_amdgcn_mfma_f32_16x16x32_bf16(af, b1, acc1, 0, 0, 0);
    }
    int tokl = mt * 16 + l4 * 4;
#pragma unroll
    for (int i = 0; i < 4; ++i) {
      gin[tokl + i][q0 + l15] = acc0[i];
      gin[tokl + i][q0 + 16 + l15] = acc1[i];
    }
  }
  __syncthreads();

  // ---- phase 3: gate = sigmoid(gin * Wg^T + bg)
  bf16x8 afr[2][4];
#pragma unroll
  for (int mt = 0; mt < 2; ++mt)
#pragma unroll
    for (int ks = 0; ks < 4; ++ks)
      afr[mt][ks] = load_bf8(&gin[mt * 16 + l15][ks * 32 + l4 * 8]);

  const float* wgb = Wg + (size_t)l15 * 128 + l4 * 8;
#pragma unroll
  for (int j = 0; j < 8; ++j) {
    const int ht = w * 8 + j;                    // h-tile 0..31
    const float* wgp = wgb + (size_t)ht * 16 * 128;
    f32x4 acc0 = {0.f, 0.f, 0.f, 0.f};
    f32x4 acc1 = {0.f, 0.f, 0.f, 0.f};
#pragma unroll
    for (int ks = 0; ks < 4; ++ks) {
      bf16x8 bf = load_bf8(wgp + ks * 32);
      acc0 = __builtin_amdgcn_mfma_f32_16x16x32_bf16(afr[0][ks], bf, acc0, 0, 0, 0);
      acc1 = __builtin_amdgcn_mfma_f32_16x16x32_bf16(afr[1][ks], bf, acc1, 0, 0, 0);
    }
    const int h = ht * 16 + l15;
    const float bgv = bg[h];
#pragma unroll
    for (int mt = 0; mt < 2; ++mt) {
      f32x4 a = mt ? acc1 : acc0;
#pragma unroll
      for (int i = 0; i < 4; ++i) {
        int tok = tok0 + mt * 16 + l4 * 4 + i;
        gate_out[(size_t)tok * DHS + h] = sigmoidf_(a[i] + bgv);
      }
    }
  }
}

// ---------------------------------------------------------------------------
// K2: streaming rewrite of ALL of S (float4 grid-stride), region-conditional.
//   Hub region multiplies by gate read from d_out (written by K1 this call).
//   Region boundaries are multiples of 64 floats -> every float4 in 1 region.
// ---------------------------------------------------------------------------
__global__ __launch_bounds__(256) void cw_write_kernel(
    const float* __restrict__ S,
    const float* __restrict__ w_spoke, const float* __restrict__ w_hub_priv,
    const float* __restrict__ w_hub_shared, const float* __restrict__ tg,
    const int* __restrict__ lip, const float* __restrict__ gate,
    float* __restrict__ outS)
{
  const int li = *lip;
  const unsigned sp0 = (unsigned)(li * 32), sp1 = sp0 + 32u;          // spoke
  const unsigned hp0 = 768u + (unsigned)(li * 16), hp1 = hp0 + 16u;   // hub_priv
  const unsigned hs0 = 1152u, hs1 = 1280u;                            // hub_shared
  const unsigned tg0 = 1280u + (unsigned)(li * 16), tg1 = tg0 + 16u;  // tag
  const unsigned rowq = DSZ / 4;                 // 1664
  const unsigned total = (unsigned)NTOK * rowq;  // 27262976

  const float4* S4 = reinterpret_cast<const float4*>(S);
  const float4* SP4 = reinterpret_cast<const float4*>(w_spoke);
  const float4* HP4 = reinterpret_cast<const float4*>(w_hub_priv);
  const float4* HS4 = reinterpret_cast<const float4*>(w_hub_shared);
  const float4* TG4 = reinterpret_cast<const float4*>(tg);
  const float4* G4 = reinterpret_cast<const float4*>(gate);
  float4* O4 = reinterpret_cast<float4*>(outS);

  for (unsigned i = blockIdx.x * 256u + threadIdx.x; i < total;
       i += gridDim.x * 256u) {
    unsigned tok = i / rowq;            // const-div -> magic multiply
    unsigned c = i - tok * rowq;
    float4 s = S4[i];
    float4 o = s;
    if (c >= hs0 && c < hs1) {
      unsigned off = tok * 128u + (c - hs0);
      float4 g = G4[off];
      float4 v = HS4[off];
      o.x = s.x * g.x + v.x;
      o.y = s.y * g.y + v.y;
      o.z = s.z * g.z + v.z;
      o.w = s.w * g.w + v.w;
    } else if (c >= sp0 && c < sp1) {
      float4 v = SP4[tok * 32u + (c - sp0)];
      o.x += v.x; o.y += v.y; o.z += v.z; o.w += v.w;
    } else if (c >= hp0 && c < hp1) {
      float4 v = HP4[tok * 16u + (c - hp0)];
      o.x += v.x; o.y += v.y; o.z += v.z; o.w += v.w;
    } else if (c >= tg0 && c < tg1) {
      float4 v = TG4[tok * 16u + (c - tg0)];
      o.x += v.x; o.y += v.y; o.z += v.z; o.w += v.w;
    }
    O4[i] = o;
  }
}

extern "C" void kernel_launch(void* const* d_in, const int* in_sizes, int n_in,
                              void* d_out, int out_size, void* d_ws, size_t ws_size,
                              hipStream_t stream) {
  (void)in_sizes; (void)n_in; (void)out_size; (void)d_ws; (void)ws_size;
  const float* S            = (const float*)d_in[0];
  const float* H            = (const float*)d_in[1];
  const float* w_spoke      = (const float*)d_in[2];
  const float* w_hub_priv   = (const float*)d_in[3];
  const float* w_hub_shared = (const float*)d_in[4];
  const float* tg           = (const float*)d_in[5];
  const float* Wq           = (const float*)d_in[6];
  const float* Wg           = (const float*)d_in[7];
  const float* bg           = (const float*)d_in[8];
  const int*   lip          = (const int*)d_in[9];

  float* outS = (float*)d_out;
  float* gate_out = outS + (size_t)NTOK * DSZ;

  cw_gate_kernel<<<NTOK / 32, 256, 0, stream>>>(S, H, Wq, Wg, bg, lip, gate_out);
  cw_write_kernel<<<4096, 256, 0, stream>>>(S, w_spoke, w_hub_priv, w_hub_shared,
                                            tg, lip, gate_out, outS);
}

// Round 5
// 325.432 us; speedup vs baseline: 1.3024x; 1.0058x over previous
//
#include <hip/hip_runtime.h>
#include <hip/hip_bf16.h>

// CognitiveWorkspace — single fused kernel.
// Per block (32 tokens, 256 threads):
//   ph1: mean_tag -> gin[tok][64..127]                  (LDS)
//   ph2: query = H*Wq^T  (bf16 MFMA, K=2048) -> gin[tok][0..63]
//   ph3: gate = sigmoid(gin*Wg^T + bg) (bf16 MFMA, K=128)
//        -> gate_out;  out_hub = S_hub*gate + w_hub_shared  (from registers)
//   ph4: stream non-hub 6144 floats/row of S -> out with spoke/priv/tag adds
// Single kernel, single writer per output element.

#define DM 2048      // d_model
#define DSZ 6656     // D_S
#define HUBOFF 4608  // hub_shared offset (floats)
#define TAGOFF 5120
#define NTOK 16384   // B*T
#define DHS 512      // d_hub_shared

typedef __attribute__((ext_vector_type(8))) short bf16x8;
typedef __attribute__((ext_vector_type(4))) float f32x4;

__device__ __forceinline__ float sigmoidf_(float x) {
  return 1.0f / (1.0f + __expf(-x));
}
__device__ __forceinline__ short f2bf(float x) {
  return (short)__bfloat16_as_ushort(__float2bfloat16(x));
}
__device__ __forceinline__ bf16x8 load_bf8(const float* p) {
  float4 a = *reinterpret_cast<const float4*>(p);
  float4 b = *reinterpret_cast<const float4*>(p + 4);
  bf16x8 r;
  r[0] = f2bf(a.x); r[1] = f2bf(a.y); r[2] = f2bf(a.z); r[3] = f2bf(a.w);
  r[4] = f2bf(b.x); r[5] = f2bf(b.y); r[6] = f2bf(b.z); r[7] = f2bf(b.w);
  return r;
}

// MFMA 16x16x32 bf16 layouts (m89-verified): A/B: row(col)=lane&15,
// k=(lane>>4)*8+e;  C/D: col=lane&15, row=(lane>>4)*4+reg.
__global__ __launch_bounds__(256) void cw_fused_kernel(
    const float* __restrict__ S, const float* __restrict__ H,
    const float* __restrict__ Wq, const float* __restrict__ Wg,
    const float* __restrict__ bg, const float* __restrict__ whs,
    const float* __restrict__ w_spoke, const float* __restrict__ w_hub_priv,
    const float* __restrict__ tg, const int* __restrict__ lip,
    float* __restrict__ outS, float* __restrict__ gate_out)
{
  __shared__ float gin[32][132];   // stride 132 -> 2-way bank alias (free)

  const int tid = threadIdx.x;
  const int li = *lip;
  const int start = (li > 8) ? (li - 8) : 0;
  const int ntags = li - start;
  const float tscale = (ntags > 0) ? (1.0f / (float)ntags) : 0.0f;
  const int trs = TAGOFF + start * 64;
  const int tok0 = blockIdx.x * 32;

  // ---- ph1: mean over past tags
#pragma unroll
  for (int r = 0; r < 8; ++r) {
    int o = r * 256 + tid;          // 32 tok x 64 d
    int tk = o >> 6, d = o & 63;
    const float* sp = S + (size_t)(tok0 + tk) * DSZ + trs + d;
    float acc = 0.f;
    for (int g = 0; g < ntags; ++g) acc += sp[g * 64];
    gin[tk][64 + d] = acc * tscale;
  }

  const int w = tid >> 6;
  const int l = tid & 63;
  const int l15 = l & 15, l4 = l >> 4;

  // ---- ph2: query = H * Wq^T  (wave tiles: mt = w&1, q-tiles (w>>1)*2,+1)
  {
    const int mt = w & 1;
    const int q0 = (w >> 1) * 32;
    const float* ha  = H + (size_t)(tok0 + mt * 16 + l15) * DM + l4 * 8;
    const float* wq0 = Wq + (size_t)(q0 + l15) * DM + l4 * 8;
    const float* wq1 = wq0 + (size_t)16 * DM;
    f32x4 acc0 = {0.f, 0.f, 0.f, 0.f};
    f32x4 acc1 = {0.f, 0.f, 0.f, 0.f};
#pragma unroll 2
    for (int ks = 0; ks < 64; ++ks) {
      bf16x8 af = load_bf8(ha + ks * 32);
      bf16x8 b0 = load_bf8(wq0 + ks * 32);
      bf16x8 b1 = load_bf8(wq1 + ks * 32);
      acc0 = __builtin_amdgcn_mfma_f32_16x16x32_bf16(af, b0, acc0, 0, 0, 0);
      acc1 = __builtin_amdgcn_mfma_f32_16x16x32_bf16(af, b1, acc1, 0, 0, 0);
    }
    int tokl = mt * 16 + l4 * 4;
#pragma unroll
    for (int i = 0; i < 4; ++i) {
      gin[tokl + i][q0 + l15] = acc0[i];
      gin[tokl + i][q0 + 16 + l15] = acc1[i];
    }
  }
  __syncthreads();

  // ---- ph3: gate = sigmoid(gin * Wg^T + bg); hub epilogue from registers
  bf16x8 afr[2][4];
#pragma unroll
  for (int mt = 0; mt < 2; ++mt)
#pragma unroll
    for (int ks = 0; ks < 4; ++ks)
      afr[mt][ks] = load_bf8(&gin[mt * 16 + l15][ks * 32 + l4 * 8]);

  const float* wgb = Wg + (size_t)l15 * 128 + l4 * 8;
#pragma unroll
  for (int j = 0; j < 8; ++j) {
    const int ht = w * 8 + j;                    // h-tile 0..31
    const float* wgp = wgb + (size_t)ht * 16 * 128;
    f32x4 acc0 = {0.f, 0.f, 0.f, 0.f};
    f32x4 acc1 = {0.f, 0.f, 0.f, 0.f};
#pragma unroll
    for (int ks = 0; ks < 4; ++ks) {
      bf16x8 bf = load_bf8(wgp + ks * 32);
      acc0 = __builtin_amdgcn_mfma_f32_16x16x32_bf16(afr[0][ks], bf, acc0, 0, 0, 0);
      acc1 = __builtin_amdgcn_mfma_f32_16x16x32_bf16(afr[1][ks], bf, acc1, 0, 0, 0);
    }
    const int h = ht * 16 + l15;
    const float bgv = bg[h];
#pragma unroll
    for (int mt = 0; mt < 2; ++mt) {
      f32x4 a = mt ? acc1 : acc0;
#pragma unroll
      for (int i = 0; i < 4; ++i) {
        int tok = tok0 + mt * 16 + l4 * 4 + i;
        float g = sigmoidf_(a[i] + bgv);
        gate_out[(size_t)tok * DHS + h] = g;
        size_t so = (size_t)tok * DSZ + HUBOFF + h;
        outS[so] = S[so] * g + whs[(size_t)tok * DHS + h];
      }
    }
  }

  // ---- ph4: stream non-hub quads of this block's 32 rows
  const unsigned sp0 = (unsigned)(li * 32), sp1 = sp0 + 32u;          // spoke
  const unsigned hp0 = 768u + (unsigned)(li * 16), hp1 = hp0 + 16u;   // hub_priv
  const unsigned tg0 = 1280u + (unsigned)(li * 16), tg1 = tg0 + 16u;  // tag

  const float4* S4 = reinterpret_cast<const float4*>(S);
  const float4* SP4 = reinterpret_cast<const float4*>(w_spoke);
  const float4* HP4 = reinterpret_cast<const float4*>(w_hub_priv);
  const float4* TG4 = reinterpret_cast<const float4*>(tg);
  float4* O4 = reinterpret_cast<float4*>(outS);

  for (int rr = 0; rr < 32; ++rr) {
    const int tok = tok0 + rr;
    const size_t rowb = (size_t)tok * 1664u;
#pragma unroll
    for (int k = 0; k < 6; ++k) {
      unsigned c = (unsigned)(k * 256 + tid);            // 0..1535
      unsigned cp = c + ((c >= 1152u) ? 128u : 0u);      // skip hub quads
      size_t idx = rowb + cp;
      float4 s = S4[idx];
      float4 o = s;
      if (cp >= sp0 && cp < sp1) {
        float4 v = SP4[(size_t)tok * 32u + (cp - sp0)];
        o.x += v.x; o.y += v.y; o.z += v.z; o.w += v.w;
      } else if (cp >= hp0 && cp < hp1) {
        float4 v = HP4[(size_t)tok * 16u + (cp - hp0)];
        o.x += v.x; o.y += v.y; o.z += v.z; o.w += v.w;
      } else if (cp >= tg0 && cp < tg1) {
        float4 v = TG4[(size_t)tok * 16u + (cp - tg0)];
        o.x += v.x; o.y += v.y; o.z += v.z; o.w += v.w;
      }
      O4[idx] = o;
    }
  }
}

extern "C" void kernel_launch(void* const* d_in, const int* in_sizes, int n_in,
                              void* d_out, int out_size, void* d_ws, size_t ws_size,
                              hipStream_t stream) {
  (void)in_sizes; (void)n_in; (void)out_size; (void)d_ws; (void)ws_size;
  const float* S            = (const float*)d_in[0];
  const float* H            = (const float*)d_in[1];
  const float* w_spoke      = (const float*)d_in[2];
  const float* w_hub_priv   = (const float*)d_in[3];
  const float* w_hub_shared = (const float*)d_in[4];
  const float* tg           = (const float*)d_in[5];
  const float* Wq           = (const float*)d_in[6];
  const float* Wg           = (const float*)d_in[7];
  const float* bg           = (const float*)d_in[8];
  const int*   lip          = (const int*)d_in[9];

  float* outS = (float*)d_out;
  float* gate_out = outS + (size_t)NTOK * DSZ;

  cw_fused_kernel<<<NTOK / 32, 256, 0, stream>>>(
      S, H, Wq, Wg, bg, w_hub_shared, w_spoke, w_hub_priv, tg, lip,
      outS, gate_out);
}